// Round 1
// baseline (73.079 us; speedup 1.0000x reference)
//
#include <hip/hip_runtime.h>

// DCN cross layers, restructured via the affine decomposition:
//   x_l = alpha_l * x0 + v_l          (alpha_0 = 1, v_0 = 0)
//   s_l = x_l . W_l = alpha_l * d_l + e_l
//       d_l = x0 . W_l               (per-row scalar — all L computable from x0 in parallel)
//       e_l = v_l . W_l              (row-independent; v_l = sum_{j<l} (b_lin_j + bias_j))
//   alpha_{l+1} = alpha_l + s_l ;  v_{l+1} = v_l + c_l ;  out = alpha_L * x0 + v_L
//
// This removes the inter-layer serial dependency of the wave reductions:
// one wave per row does TWO independent packed-float4 6-step __shfl_xor
// reductions (d0..d3 and e1..e3) instead of four serially-dependent ones.
// Critical path: ~6 dependent cross-lane steps instead of ~24.

__device__ __forceinline__ float dot4(float4 a, float4 b) {
    return fmaf(a.x, b.x, fmaf(a.y, b.y, fmaf(a.z, b.z, a.w * b.w)));
}

__global__ __launch_bounds__(256) void cross_kernel(
    const float* __restrict__ x,
    const float* __restrict__ W,
    const float* __restrict__ b_lin,
    const float* __restrict__ bias,
    float* __restrict__ out,
    int B, int L)
{
    const int wave = threadIdx.x >> 6;     // 0..3
    const int lane = threadIdx.x & 63;     // 0..63
    const int row  = blockIdx.x * 4 + wave;
    if (row >= B) return;

    const float4 zero4 = make_float4(0.f, 0.f, 0.f, 0.f);

    // x0: this lane's 4 contiguous elements of the row (coalesced 1 KB/wave)
    const float4* xrow = (const float4*)(x + (size_t)row * 256);
    const float4 x0 = xrow[lane];

    const float4* W4 = (const float4*)W;     // [L][64] float4
    const float4* B4 = (const float4*)bias;  // [L][64] float4

    // W rows (L2/L1-resident after first touch; uniform addresses per wave)
    const float4 w0 = (L > 0) ? W4[0 * 64 + lane] : zero4;
    const float4 w1 = (L > 1) ? W4[1 * 64 + lane] : zero4;
    const float4 w2 = (L > 2) ? W4[2 * 64 + lane] : zero4;
    const float4 w3 = (L > 3) ? W4[3 * 64 + lane] : zero4;

    // Per-lane partial dots d_l = x0 . W_l  — all four independent
    float4 d;
    d.x = dot4(x0, w0);
    d.y = dot4(x0, w1);
    d.z = dot4(x0, w2);
    d.w = dot4(x0, w3);

    // Prefix sums v_l of c_j = b_lin[j] + bias[j], and e_l = v_l . W_l partials
    float4 v = zero4;   // running per-lane slice of v_l; ends as v_L
    float4 e = zero4;   // e.x=e_1, e.y=e_2, e.z=e_3 per-lane partials
    if (L > 0) {
        const float bl = b_lin[0];
        float4 c = B4[0 * 64 + lane];
        v.x = c.x + bl; v.y = c.y + bl; v.z = c.z + bl; v.w = c.w + bl;
    }
    if (L > 1) {
        e.x = dot4(v, w1);
        const float bl = b_lin[1];
        float4 c = B4[1 * 64 + lane];
        v.x += c.x + bl; v.y += c.y + bl; v.z += c.z + bl; v.w += c.w + bl;
    }
    if (L > 2) {
        e.y = dot4(v, w2);
        const float bl = b_lin[2];
        float4 c = B4[2 * 64 + lane];
        v.x += c.x + bl; v.y += c.y + bl; v.z += c.z + bl; v.w += c.w + bl;
    }
    if (L > 3) {
        e.z = dot4(v, w3);
        const float bl = b_lin[3];
        float4 c = B4[3 * 64 + lane];
        v.x += c.x + bl; v.y += c.y + bl; v.z += c.z + bl; v.w += c.w + bl;
    }

    // Two independent packed 6-step butterfly reductions (chains interleave;
    // the 7 shuffles per step are mutually independent -> pipeline in DS/VALU)
    #pragma unroll
    for (int off = 32; off > 0; off >>= 1) {
        d.x += __shfl_xor(d.x, off, 64);
        d.y += __shfl_xor(d.y, off, 64);
        d.z += __shfl_xor(d.z, off, 64);
        d.w += __shfl_xor(d.w, off, 64);
        e.x += __shfl_xor(e.x, off, 64);
        e.y += __shfl_xor(e.y, off, 64);
        e.z += __shfl_xor(e.z, off, 64);
    }

    // Uniform scalar recurrence: alpha_{l+1} = alpha_l + (alpha_l * d_l + e_l)
    float a = 1.0f;
    if (L > 0) a += d.x;                    // e_0 = 0
    if (L > 1) a += fmaf(a, d.y, e.x);
    if (L > 2) a += fmaf(a, d.z, e.y);
    if (L > 3) a += fmaf(a, d.w, e.z);

    // out = alpha_L * x0 + v_L
    float4 o;
    o.x = fmaf(a, x0.x, v.x);
    o.y = fmaf(a, x0.y, v.y);
    o.z = fmaf(a, x0.z, v.z);
    o.w = fmaf(a, x0.w, v.w);
    ((float4*)(out + (size_t)row * 256))[lane] = o;
}

extern "C" void kernel_launch(void* const* d_in, const int* in_sizes, int n_in,
                              void* d_out, int out_size, void* d_ws, size_t ws_size,
                              hipStream_t stream) {
    const float* x     = (const float*)d_in[0];
    const float* W     = (const float*)d_in[1];
    const float* b_lin = (const float*)d_in[2];
    const float* bias  = (const float*)d_in[3];
    float* out = (float*)d_out;

    const int L = in_sizes[2];          // 4
    const int D = in_sizes[1] / L;      // 256 (kernel assumes 256)
    const int B = in_sizes[0] / D;      // 8192

    const int rows_per_block = 4;       // 4 waves x 64 lanes, one row per wave
    const int grid = (B + rows_per_block - 1) / rows_per_block;
    cross_kernel<<<grid, 256, 0, stream>>>(x, W, b_lin, bias, out, B, L);
}

// Round 2
// 68.746 us; speedup vs baseline: 1.0630x; 1.0630x over previous
//
#include <hip/hip_runtime.h>

// DCN cross layers via the affine decomposition:
//   x_l = alpha_l * x0 + v_l          (alpha_0 = 1, v_0 = 0)
//   s_l = alpha_l * d_l + e_l,  d_l = x0 . W_l,  e_l = v_l . W_l
//   alpha_{l+1} = alpha_l + s_l ;  v_{l+1} = v_l + b_lin_l + bias_l
//   out = alpha_L * x0 + v_L
//
// v_l is row-independent, so the only cross-lane work is TWO independent
// packed reductions (d0..d3, e1..e3) -> 6 dependent shuffle steps total
// instead of 4 serial 6-step reductions (24 dependent steps).
//
// Register discipline (round-2 fix): each W row is consumed by its two dots
// and dies immediately; each bias row dies into v. Peak live set ~30 VGPR.
// __launch_bounds__(256, 8): force <=64 VGPR so the 8192-wave grid fits in
// ONE residency pass (32 waves/CU) -- round 1 plausibly crossed the 64-VGPR
// cliff and halved occupancy.

__device__ __forceinline__ float dot4(float4 a, float4 b) {
    return fmaf(a.x, b.x, fmaf(a.y, b.y, fmaf(a.z, b.z, a.w * b.w)));
}

__global__ __launch_bounds__(256, 8) void cross_kernel(
    const float* __restrict__ x,
    const float* __restrict__ W,
    const float* __restrict__ b_lin,
    const float* __restrict__ bias,
    float* __restrict__ out,
    int B, int L)
{
    const int wave = threadIdx.x >> 6;     // 0..3
    const int lane = threadIdx.x & 63;     // 0..63
    const int row  = blockIdx.x * 4 + wave;
    if (row >= B) return;

    // x0: this lane's 4 contiguous elements of the row (coalesced 1 KB/wave)
    const float4 x0 = ((const float4*)(x + (size_t)row * 256))[lane];

    const float4* W4 = (const float4*)W;     // [L][64] float4
    const float4* B4 = (const float4*)bias;  // [L][64] float4

    float d0 = 0.f, d1 = 0.f, d2 = 0.f, d3 = 0.f;   // d_l = x0 . W_l partials
    float e1 = 0.f, e2 = 0.f, e3 = 0.f;             // e_l = v_l . W_l partials
    float4 v = make_float4(0.f, 0.f, 0.f, 0.f);     // running v_l slice

    if (L > 0) {
        float4 w = W4[0 * 64 + lane];
        d0 = dot4(x0, w);                            // w dies here
        float4 c = B4[0 * 64 + lane];
        const float bl = b_lin[0];
        v.x = c.x + bl; v.y = c.y + bl; v.z = c.z + bl; v.w = c.w + bl;
    }
    if (L > 1) {
        float4 w = W4[1 * 64 + lane];
        d1 = dot4(x0, w);
        e1 = dot4(v, w);                             // v_1 . W_1
        float4 c = B4[1 * 64 + lane];
        const float bl = b_lin[1];
        v.x += c.x + bl; v.y += c.y + bl; v.z += c.z + bl; v.w += c.w + bl;
    }
    if (L > 2) {
        float4 w = W4[2 * 64 + lane];
        d2 = dot4(x0, w);
        e2 = dot4(v, w);                             // v_2 . W_2
        float4 c = B4[2 * 64 + lane];
        const float bl = b_lin[2];
        v.x += c.x + bl; v.y += c.y + bl; v.z += c.z + bl; v.w += c.w + bl;
    }
    if (L > 3) {
        float4 w = W4[3 * 64 + lane];
        d3 = dot4(x0, w);
        e3 = dot4(v, w);                             // v_3 . W_3
        float4 c = B4[3 * 64 + lane];
        const float bl = b_lin[3];
        v.x += c.x + bl; v.y += c.y + bl; v.z += c.z + bl; v.w += c.w + bl;
    }

    // Two independent packed butterfly reductions; 6 dependent steps, the 7
    // shuffles within a step are mutually independent and pipeline.
    #pragma unroll
    for (int off = 32; off > 0; off >>= 1) {
        d0 += __shfl_xor(d0, off, 64);
        d1 += __shfl_xor(d1, off, 64);
        d2 += __shfl_xor(d2, off, 64);
        d3 += __shfl_xor(d3, off, 64);
        e1 += __shfl_xor(e1, off, 64);
        e2 += __shfl_xor(e2, off, 64);
        e3 += __shfl_xor(e3, off, 64);
    }

    // Uniform scalar recurrence: alpha_{l+1} = alpha_l + (alpha_l*d_l + e_l).
    // L==0 degenerates correctly: d0=0, v=0 -> a=1, out=x0.
    float a = 1.0f + d0;                    // e_0 = 0
    if (L > 1) a += fmaf(a, d1, e1);
    if (L > 2) a += fmaf(a, d2, e2);
    if (L > 3) a += fmaf(a, d3, e3);

    // out = alpha_L * x0 + v_L
    float4 o;
    o.x = fmaf(a, x0.x, v.x);
    o.y = fmaf(a, x0.y, v.y);
    o.z = fmaf(a, x0.z, v.z);
    o.w = fmaf(a, x0.w, v.w);
    ((float4*)(out + (size_t)row * 256))[lane] = o;
}

extern "C" void kernel_launch(void* const* d_in, const int* in_sizes, int n_in,
                              void* d_out, int out_size, void* d_ws, size_t ws_size,
                              hipStream_t stream) {
    const float* x     = (const float*)d_in[0];
    const float* W     = (const float*)d_in[1];
    const float* b_lin = (const float*)d_in[2];
    const float* bias  = (const float*)d_in[3];
    float* out = (float*)d_out;

    const int L = in_sizes[2];          // 4
    const int D = in_sizes[1] / L;      // 256 (kernel assumes 256)
    const int B = in_sizes[0] / D;      // 8192

    const int rows_per_block = 4;       // 4 waves x 64 lanes, one row per wave
    const int grid = (B + rows_per_block - 1) / rows_per_block;
    cross_kernel<<<grid, 256, 0, stream>>>(x, W, b_lin, bias, out, B, L);
}